// Round 12
// baseline (153.277 us; speedup 1.0000x reference)
//
#include <hip/hip_runtime.h>
#include <hip/hip_bf16.h>
#include <hip/hip_fp16.h>

#define NN 512
#define DD 64
#define TOPK 20
#define BB 128

// =============== KDOT_PRE: f64 heavy work, isolated register budget ============
__global__ __launch_bounds__(256) void kdot_pre(const float* __restrict__ emb,
                                                const float* __restrict__ attn_w,
                                                double* __restrict__ cosM,
                                                double* __restrict__ nrm,
                                                float* __restrict__ es_src,
                                                float* __restrict__ es_dst,
                                                double* __restrict__ gstats) {
    __shared__ __align__(16) char smem[17408];
    const int bid = blockIdx.x, t = threadIdx.x;

    if (bid < 256) {
        const int bi0 = (bid >> 4) * 32;
        const int bj0 = (bid & 15) * 32;
        float4* A4 = (float4*)smem;               // [32][17]
        float4* B4 = (float4*)(smem + 8704);      // [32][17]
        const float4* e4 = (const float4*)emb;

        for (int m = t; m < 512; m += 256) {
            const int r = m >> 4, c = m & 15;
            A4[r * 17 + c] = e4[(bi0 + r) * 16 + c];
            B4[r * 17 + c] = e4[(bj0 + r) * 16 + c];
        }
        __syncthreads();

        const int tr = t >> 4, tc = t & 15;
        #pragma unroll
        for (int rr = 0; rr < 2; ++rr) {
            #pragma unroll
            for (int cc = 0; cc < 2; ++cc) {
                const int r  = tr + rr * 16;
                const int cl = tc + cc * 16;
                double dot = 0.0;
                #pragma unroll
                for (int c = 0; c < 16; ++c) {
                    const float4 a = A4[r * 17 + c];
                    const float4 b = B4[cl * 17 + c];
                    dot += (double)a.x * (double)b.x;
                    dot += (double)a.y * (double)b.y;
                    dot += (double)a.z * (double)b.z;
                    dot += (double)a.w * (double)b.w;
                }
                cosM[(long)(bi0 + r) * NN + (bj0 + cl)] = dot;
            }
        }
    } else if (bid < 258) {
        const int j = (bid - 256) * 256 + t;
        const float4* e4 = (const float4*)emb;
        double s = 0.0;
        #pragma unroll
        for (int c = 0; c < 16; ++c) {
            const float4 v = e4[j * 16 + c];
            const double vx = v.x, vy = v.y, vz = v.z, vw = v.w;
            s += vx * vx; s += vy * vy; s += vz * vz; s += vw * vw;
        }
        nrm[j] = sqrt(s);
        if (bid == 256 && t < 128) gstats[t] = 0.0;
    } else {
        const int j = (bid - 258) * 256 + t;
        float s1 = 0.f, s2 = 0.f;
        #pragma unroll
        for (int c = 0; c < 64; ++c) {
            const float w = emb[j * 64 + c];
            s1 += w * attn_w[64 + c];
            s2 += w * attn_w[192 + c];
        }
        es_src[j] = s1;
        es_dst[j] = s2;
    }
}

// =============== KGEMM_SEL: lean f32 GEMM (8x4 tile) + topk selection ==========
// blocks 0..511  : GEMM 128x64 tile; per-thread 8 rows x 4 cols. Same per-(i,j)
//                  accumulation expressions as R11 -> z bit-identical.
// blocks 512..639: ksel (reads cosM/nrm from kdot_pre).
__global__ __launch_bounds__(256) void kgemm_sel(const float* __restrict__ data,
                                                 const float* __restrict__ fc_w,
                                                 const float* __restrict__ fc_b,
                                                 const float* __restrict__ attn_w,
                                                 const double* __restrict__ cosM,
                                                 const double* __restrict__ nrmArr,
                                                 float* __restrict__ z,
                                                 float* __restrict__ zsrc,
                                                 float* __restrict__ zdst,
                                                 int* __restrict__ topk) {
    __shared__ __align__(16) char smem[55296];
    const int bid = blockIdx.x, t = threadIdx.x;

    if (bid < 512) {
        float (*As)[72]  = (float(*)[72])smem;             // 128 rows, 36864 B
        float (*WsT)[72] = (float(*)[72])(smem + 36864);   // 64 rows,  18432 B
        const long r0 = (long)bid * 128;
        const float4* data4 = (const float4*)data;
        const float4* fcw4  = (const float4*)fc_w;

        for (int m = t; m < 2048; m += 256) {
            const int r = m >> 4, c4 = m & 15;
            *(float4*)&As[r][c4 * 4] = data4[(r0 + r) * 16 + c4];
        }
        for (int m = t; m < 1024; m += 256) {
            const int d = m >> 4, f4 = m & 15;
            float4 v = fcw4[d * 16 + f4];
            WsT[f4 * 4 + 0][d] = v.x;
            WsT[f4 * 4 + 1][d] = v.y;
            WsT[f4 * 4 + 2][d] = v.z;
            WsT[f4 * 4 + 3][d] = v.w;
        }
        __syncthreads();

        const int tr = t >> 4, tc = t & 15;   // rows tr*8..+7, cols tc*4..+3
        float acc[8][4] = {};
        for (int k0 = 0; k0 < 64; k0 += 4) {
            float4 a4[8], b4[4];
            #pragma unroll
            for (int i = 0; i < 8; ++i) a4[i] = *(float4*)&As[tr * 8 + i][k0];
            #pragma unroll
            for (int kk = 0; kk < 4; ++kk) b4[kk] = *(float4*)&WsT[k0 + kk][tc * 4];
            #pragma unroll
            for (int i = 0; i < 8; ++i) {
                acc[i][0] += a4[i].x * b4[0].x + a4[i].y * b4[1].x + a4[i].z * b4[2].x + a4[i].w * b4[3].x;
                acc[i][1] += a4[i].x * b4[0].y + a4[i].y * b4[1].y + a4[i].z * b4[2].y + a4[i].w * b4[3].y;
                acc[i][2] += a4[i].x * b4[0].z + a4[i].y * b4[1].z + a4[i].z * b4[2].z + a4[i].w * b4[3].z;
                acc[i][3] += a4[i].x * b4[0].w + a4[i].y * b4[1].w + a4[i].z * b4[2].w + a4[i].w * b4[3].w;
            }
        }
        float bias[4], aw0[4], aw2[4];
        #pragma unroll
        for (int j = 0; j < 4; ++j) {
            bias[j] = fc_b[tc * 4 + j];
            aw0[j]  = attn_w[tc * 4 + j];
            aw2[j]  = attn_w[128 + tc * 4 + j];
        }
        float zb[8][4];
        #pragma unroll
        for (int i = 0; i < 8; ++i) {
            #pragma unroll
            for (int j = 0; j < 4; ++j) zb[i][j] = acc[i][j] + bias[j];
            float4 vv; vv.x = zb[i][0]; vv.y = zb[i][1]; vv.z = zb[i][2]; vv.w = zb[i][3];
            *(float4*)&z[(r0 + tr * 8 + i) * 64 + tc * 4] = vv;
        }
        __syncthreads();   // all As/WsT reads done -> safe to alias

        float (*redA)[17] = (float(*)[17])smem;            // [128][17], aliases As
        float (*redB)[17] = (float(*)[17])(smem + 8704);
        #pragma unroll
        for (int i = 0; i < 8; ++i) {
            redA[tr * 8 + i][tc] = zb[i][0] * aw0[0] + zb[i][1] * aw0[1] + zb[i][2] * aw0[2] + zb[i][3] * aw0[3];
            redB[tr * 8 + i][tc] = zb[i][0] * aw2[0] + zb[i][1] * aw2[1] + zb[i][2] * aw2[2] + zb[i][3] * aw2[3];
        }
        __syncthreads();
        if (t < 128) {
            float sA = 0.f, sB = 0.f;
            #pragma unroll
            for (int k = 0; k < 16; ++k) { sA += redA[t][k]; sB += redB[t][k]; }
            zsrc[r0 + t] = sA;
            zdst[r0 + t] = sB;
        }
    } else {
        // ---------------- ksel: top-20, one wave per node ----------------------
        const int wid = t >> 6, lane = t & 63;
        const int i = (bid - 512) * 4 + wid;

        const double nrm_i = nrmArr[i];
        double v[8];
        #pragma unroll
        for (int s = 0; s < 8; ++s)
            v[s] = cosM[(long)i * NN + s * 64 + lane] / (nrm_i * nrmArr[s * 64 + lane]);

        for (int k = 0; k < TOPK; ++k) {
            double bv = v[0]; int bs = 0;
            #pragma unroll
            for (int s = 1; s < 8; ++s) if (v[s] > bv) { bv = v[s]; bs = s; }
            int bi = bs * 64 + lane;
            #pragma unroll
            for (int off = 32; off > 0; off >>= 1) {
                double ov = __shfl_xor(bv, off);
                int    oi = __shfl_xor(bi, off);
                if (ov > bv || (ov == bv && oi < bi)) { bv = ov; bi = oi; }
            }
            if (lane == 0) topk[i * TOPK + k] = bi;
            if ((bi & 63) == lane) v[bi >> 6] = -1e300;
        }
    }
}

// =============== K3: LDS-staged gather + one-shot softmax + BN atomics =========
__global__ __launch_bounds__(256) void k3_attn(const float* __restrict__ z,
                                               const float* __restrict__ zsrc,
                                               const float* __restrict__ zdst,
                                               const float* __restrict__ es_src,
                                               const float* __restrict__ es_dst,
                                               const int* __restrict__ topk,
                                               const float* __restrict__ emb,
                                               const float* __restrict__ attn_b_p,
                                               __half* __restrict__ rst,
                                               double* __restrict__ gstats) {
    __shared__ float  zs[512 * 16];          // 32 KB
    __shared__ double alf_pool[2560];        // 20 KB: alpha[256][20] / BN-reduce alias
    __shared__ unsigned short sIdx[256 * 20];// 10 KB
    float* alf = (float*)alf_pool;
    const float4* alf4 = (const float4*)alf_pool;   // rows are 80 B = 5 float4

    const int b    = blockIdx.x >> 2;
    const int dq   = blockIdx.x & 3;
    const int doff = dq * 16;
    const int t    = threadIdx.x;
    const float attn_b = *attn_b_p;
    const long b512 = (long)b * NN;

    float4* zs4 = (float4*)zs;
    for (int m = t; m < 2048; m += 256) {
        const int n = m >> 2, c4i = m & 3;
        zs4[m] = *(const float4*)(z + (b512 + n) * 64 + doff + c4i * 4);
    }
    __syncthreads();

    const int c4 = t & 3;
    const int rq = t >> 2;
    double s1[4] = {0,0,0,0}, s2[4] = {0,0,0,0};

    for (int chunk = 0; chunk < 2; ++chunk) {
        {
            const int n = chunk * 256 + t;
            const float sd = zdst[b512 + n] + es_dst[n] + attn_b;
            float ev[TOPK];
            float m0 = -1e30f;
            #pragma unroll
            for (int tt = 0; tt < TOPK; ++tt) {
                const int s = topk[n + tt * NN];   // scrambled flat edge list
                sIdx[t * TOPK + tt] = (unsigned short)s;
                float e = zsrc[b512 + s] + es_src[s] + sd;
                e = (e >= 0.f) ? e : 0.2f * e;
                ev[tt] = e;
                m0 = fmaxf(m0, e);
            }
            float dsum = 0.f;
            #pragma unroll
            for (int tt = 0; tt < TOPK; ++tt) { ev[tt] = __expf(ev[tt] - m0); dsum += ev[tt]; }
            const float inv = 1.0f / dsum;
            #pragma unroll
            for (int tt = 0; tt < TOPK; ++tt) alf[t * TOPK + tt] = ev[tt] * inv;
        }
        __syncthreads();

        #pragma unroll
        for (int it = 0; it < 4; ++it) {
            const int nl = it * 64 + rq;
            const int n  = chunk * 256 + nl;
            float4 af[5];
            #pragma unroll
            for (int q = 0; q < 5; ++q) af[q] = alf4[nl * 5 + q];
            const float* av = (const float*)af;
            float4 acc = {0.f, 0.f, 0.f, 0.f};
            #pragma unroll
            for (int tt = 0; tt < TOPK; ++tt) {
                const float a = av[tt];
                const float4 zv = zs4[(int)sIdx[nl * TOPK + tt] * 4 + c4];
                acc.x += a * zv.x; acc.y += a * zv.y; acc.z += a * zv.z; acc.w += a * zv.w;
            }
            const float4 ev = *(const float4*)&emb[n * 64 + doff + c4 * 4];
            float4 r;
            r.x = acc.x * ev.x; r.y = acc.y * ev.y; r.z = acc.z * ev.z; r.w = acc.w * ev.w;
            __half2* rh = (__half2*)&rst[(b512 + n) * 64 + doff + c4 * 4];
            rh[0] = __floats2half2_rn(r.x, r.y);
            rh[1] = __floats2half2_rn(r.z, r.w);
            s1[0] += (double)r.x; s2[0] += (double)r.x * (double)r.x;
            s1[1] += (double)r.y; s2[1] += (double)r.y * (double)r.y;
            s1[2] += (double)r.z; s2[2] += (double)r.z * (double)r.z;
            s1[3] += (double)r.w; s2[3] += (double)r.w * (double)r.w;
        }
        __syncthreads();
    }

    double* r1 = alf_pool;
    double* r2 = alf_pool + 1024;
    #pragma unroll
    for (int j = 0; j < 4; ++j) {
        r1[(c4 * 4 + j) * 64 + rq] = s1[j];
        r2[(c4 * 4 + j) * 64 + rq] = s2[j];
    }
    __syncthreads();
    if (t < 16) {
        double a = 0.0, bb = 0.0;
        for (int q = 0; q < 64; ++q) { a += r1[t * 64 + q]; bb += r2[t * 64 + q]; }
        atomicAdd(&gstats[doff + t], a);
        atomicAdd(&gstats[64 + doff + t], bb);
    }
}

// =============== K5: BN finalize (per-block) + apply + ReLU + out_w dot ========
__global__ __launch_bounds__(256) void k5_out(const __half* __restrict__ rst,
                                              const double* __restrict__ gstats,
                                              const float* __restrict__ gamma,
                                              const float* __restrict__ beta,
                                              const float* __restrict__ out_w,
                                              const float* __restrict__ out_b_p,
                                              float* __restrict__ out) {
    __shared__ float scv[64], biv[64];
    const int t = threadIdx.x;
    if (t < 64) {
        const double M = (double)BB * (double)NN;
        const double s  = gstats[t];
        const double s2 = gstats[64 + t];
        const double mu  = s / M;
        const double var = s2 / M - mu * mu;
        const float scale = (float)((double)gamma[t] / sqrt(var + 1e-5));
        scv[t] = scale;
        biv[t] = beta[t] - (float)mu * scale;
    }
    __syncthreads();

    const int wid = t >> 6, lane = t & 63;
    const float sc = scv[lane], bi = biv[lane], ow = out_w[lane];
    const float ob = *out_b_p;
    const long rowbase = (long)blockIdx.x * 16 + wid * 4;
    float v[4];
    #pragma unroll
    for (int rr = 0; rr < 4; ++rr)
        v[rr] = fmaxf(__half2float(rst[(rowbase + rr) * 64 + lane]) * sc + bi, 0.f) * ow;
    #pragma unroll
    for (int off = 32; off > 0; off >>= 1)
        #pragma unroll
        for (int rr = 0; rr < 4; ++rr) v[rr] += __shfl_down(v[rr], off);
    if (lane == 0)
        #pragma unroll
        for (int rr = 0; rr < 4; ++rr) out[rowbase + rr] = v[rr] + ob;
}

extern "C" void kernel_launch(void* const* d_in, const int* in_sizes, int n_in,
                              void* d_out, int out_size, void* d_ws, size_t ws_size,
                              hipStream_t stream) {
    const float* data   = (const float*)d_in[0];
    const float* emb    = (const float*)d_in[1];
    const float* fc_w   = (const float*)d_in[2];
    const float* fc_b   = (const float*)d_in[3];
    const float* attn_w = (const float*)d_in[4];
    const float* attn_b = (const float*)d_in[5];
    const float* gamma  = (const float*)d_in[6];
    const float* beta   = (const float*)d_in[7];
    const float* out_w  = (const float*)d_in[8];
    const float* out_b  = (const float*)d_in[9];
    float* out = (float*)d_out;

    char* ws = (char*)d_ws;
    float*  z      = (float*) (ws + 0);            // 16 MB
    __half* rst    = (__half*)(ws + 16777216);     // 8.4 MB
    float*  zsrc   = (float*) (ws + 33554432);     // 256 KB
    float*  zdst   = (float*) (ws + 33816576);     // 256 KB
    int*    topk   = (int*)   (ws + 34078720);     // 40 KB
    float*  es_src = (float*) (ws + 34119680);     // 2 KB
    float*  es_dst = (float*) (ws + 34121728);     // 2 KB
    double* gstats = (double*)(ws + 34123776);     // 1 KB
    double* nrm    = (double*)(ws + 34124800);     // 4 KB
    double* cosM   = (double*)(ws + 34131968);     // 2 MB

    kdot_pre<<<260, 256, 0, stream>>>(emb, attn_w, cosM, nrm, es_src, es_dst, gstats);
    kgemm_sel<<<640, 256, 0, stream>>>(data, fc_w, fc_b, attn_w, cosM, nrm,
                                       z, zsrc, zdst, topk);
    k3_attn<<<BB * 4, 256, 0, stream>>>(z, zsrc, zdst, es_src, es_dst, topk, emb,
                                        attn_b, rst, gstats);
    k5_out<<<4096, 256, 0, stream>>>(rst, gstats, gamma, beta, out_w, out_b, out);
}

// Round 13
// 142.240 us; speedup vs baseline: 1.0776x; 1.0776x over previous
//
#include <hip/hip_runtime.h>
#include <hip/hip_bf16.h>

#define NN 512
#define DD 64
#define TOPK 20
#define BB 128

// =============== KDOT_PRE: f64 heavy work, isolated register budget ============
// blocks 0..255 : cos numerators, 32x32 f64 dot tiles (bit-identical to R11)
// blocks 256..257: norms (f64, bit-identical order); 256 zeroes gstats
// blocks 258..259: es_src / es_dst
__global__ __launch_bounds__(256) void kdot_pre(const float* __restrict__ emb,
                                                const float* __restrict__ attn_w,
                                                double* __restrict__ cosM,
                                                double* __restrict__ nrm,
                                                float* __restrict__ es_src,
                                                float* __restrict__ es_dst,
                                                double* __restrict__ gstats) {
    __shared__ __align__(16) char smem[17408];
    const int bid = blockIdx.x, t = threadIdx.x;

    if (bid < 256) {
        const int bi0 = (bid >> 4) * 32;
        const int bj0 = (bid & 15) * 32;
        float4* A4 = (float4*)smem;               // [32][17]
        float4* B4 = (float4*)(smem + 8704);      // [32][17]
        const float4* e4 = (const float4*)emb;

        for (int m = t; m < 512; m += 256) {
            const int r = m >> 4, c = m & 15;
            A4[r * 17 + c] = e4[(bi0 + r) * 16 + c];
            B4[r * 17 + c] = e4[(bj0 + r) * 16 + c];
        }
        __syncthreads();

        const int tr = t >> 4, tc = t & 15;
        #pragma unroll
        for (int rr = 0; rr < 2; ++rr) {
            #pragma unroll
            for (int cc = 0; cc < 2; ++cc) {
                const int r  = tr + rr * 16;
                const int cl = tc + cc * 16;
                double dot = 0.0;
                #pragma unroll
                for (int c = 0; c < 16; ++c) {
                    const float4 a = A4[r * 17 + c];
                    const float4 b = B4[cl * 17 + c];
                    dot += (double)a.x * (double)b.x;
                    dot += (double)a.y * (double)b.y;
                    dot += (double)a.z * (double)b.z;
                    dot += (double)a.w * (double)b.w;
                }
                cosM[(long)(bi0 + r) * NN + (bj0 + cl)] = dot;
            }
        }
    } else if (bid < 258) {
        const int j = (bid - 256) * 256 + t;
        const float4* e4 = (const float4*)emb;
        double s = 0.0;
        #pragma unroll
        for (int c = 0; c < 16; ++c) {
            const float4 v = e4[j * 16 + c];
            const double vx = v.x, vy = v.y, vz = v.z, vw = v.w;
            s += vx * vx; s += vy * vy; s += vz * vz; s += vw * vw;
        }
        nrm[j] = sqrt(s);
        if (bid == 256 && t < 128) gstats[t] = 0.0;
    } else {
        const int j = (bid - 258) * 256 + t;
        float s1 = 0.f, s2 = 0.f;
        #pragma unroll
        for (int c = 0; c < 64; ++c) {
            const float w = emb[j * 64 + c];
            s1 += w * attn_w[64 + c];
            s2 += w * attn_w[192 + c];
        }
        es_src[j] = s1;
        es_dst[j] = s2;
    }
}

// =============== KGEMM_SEL: lean f32 GEMM + topk selection =====================
// blocks 0..1023   : GEMM 64x64 tile (R11-identical -> z bit-identical)
// blocks 1024..1151: ksel — reads cosM/nrm written by kdot_pre (prior launch).
__global__ __launch_bounds__(256) void kgemm_sel(const float* __restrict__ data,
                                                 const float* __restrict__ fc_w,
                                                 const float* __restrict__ fc_b,
                                                 const float* __restrict__ attn_w,
                                                 const double* __restrict__ cosM,
                                                 const double* __restrict__ nrmArr,
                                                 float* __restrict__ z,
                                                 float* __restrict__ zsrc,
                                                 float* __restrict__ zdst,
                                                 int* __restrict__ topk) {
    __shared__ __align__(16) char smem[34816];
    const int bid = blockIdx.x, t = threadIdx.x;

    if (bid < 1024) {
        // ---------------- GEMM 64x64 tile, float4 LDS --------------------------
        float (*As)[68]  = (float(*)[68])smem;             // 17408 B
        float (*WsT)[68] = (float(*)[68])(smem + 17408);   // 17408 B
        const long r0 = (long)bid * 64;
        const float4* data4 = (const float4*)data;
        const float4* fcw4  = (const float4*)fc_w;

        for (int m = t; m < 1024; m += 256) {
            const int r = m >> 4, c4 = m & 15;
            *(float4*)&As[r][c4 * 4] = data4[(r0 + r) * 16 + c4];
        }
        for (int m = t; m < 1024; m += 256) {
            const int d = m >> 4, f4 = m & 15;
            float4 v = fcw4[d * 16 + f4];
            WsT[f4 * 4 + 0][d] = v.x;
            WsT[f4 * 4 + 1][d] = v.y;
            WsT[f4 * 4 + 2][d] = v.z;
            WsT[f4 * 4 + 3][d] = v.w;
        }
        __syncthreads();

        const int tr = t >> 4, tc = t & 15;
        float acc[4][4] = {};
        for (int k0 = 0; k0 < 64; k0 += 4) {
            float4 a4[4], b4[4];
            #pragma unroll
            for (int i = 0; i < 4; ++i) a4[i] = *(float4*)&As[tr * 4 + i][k0];
            #pragma unroll
            for (int kk = 0; kk < 4; ++kk) b4[kk] = *(float4*)&WsT[k0 + kk][tc * 4];
            #pragma unroll
            for (int i = 0; i < 4; ++i) {
                acc[i][0] += a4[i].x * b4[0].x + a4[i].y * b4[1].x + a4[i].z * b4[2].x + a4[i].w * b4[3].x;
                acc[i][1] += a4[i].x * b4[0].y + a4[i].y * b4[1].y + a4[i].z * b4[2].y + a4[i].w * b4[3].y;
                acc[i][2] += a4[i].x * b4[0].z + a4[i].y * b4[1].z + a4[i].z * b4[2].z + a4[i].w * b4[3].z;
                acc[i][3] += a4[i].x * b4[0].w + a4[i].y * b4[1].w + a4[i].z * b4[2].w + a4[i].w * b4[3].w;
            }
        }
        float bias[4], aw0[4], aw2[4];
        #pragma unroll
        for (int j = 0; j < 4; ++j) {
            bias[j] = fc_b[tc * 4 + j];
            aw0[j]  = attn_w[tc * 4 + j];
            aw2[j]  = attn_w[128 + tc * 4 + j];
        }
        float zb[4][4];
        #pragma unroll
        for (int i = 0; i < 4; ++i) {
            #pragma unroll
            for (int j = 0; j < 4; ++j) zb[i][j] = acc[i][j] + bias[j];
            float4 vv; vv.x = zb[i][0]; vv.y = zb[i][1]; vv.z = zb[i][2]; vv.w = zb[i][3];
            *(float4*)&z[(r0 + tr * 4 + i) * 64 + tc * 4] = vv;
        }
        __syncthreads();   // all As/WsT reads done -> safe to alias

        float (*redA)[17] = (float(*)[17])smem;            // aliases As
        float (*redB)[17] = (float(*)[17])(smem + 4352);
        #pragma unroll
        for (int i = 0; i < 4; ++i) {
            redA[tr * 4 + i][tc] = zb[i][0] * aw0[0] + zb[i][1] * aw0[1] + zb[i][2] * aw0[2] + zb[i][3] * aw0[3];
            redB[tr * 4 + i][tc] = zb[i][0] * aw2[0] + zb[i][1] * aw2[1] + zb[i][2] * aw2[2] + zb[i][3] * aw2[3];
        }
        __syncthreads();
        if (t < 64) {
            float sA = 0.f, sB = 0.f;
            #pragma unroll
            for (int k = 0; k < 16; ++k) { sA += redA[t][k]; sB += redB[t][k]; }
            zsrc[r0 + t] = sA;
            zdst[r0 + t] = sB;
        }
    } else {
        // ---------------- ksel: top-20, one wave per node ----------------------
        const int wid = t >> 6, lane = t & 63;
        const int i = (bid - 1024) * 4 + wid;

        const double nrm_i = nrmArr[i];
        double v[8];
        #pragma unroll
        for (int s = 0; s < 8; ++s)
            v[s] = cosM[(long)i * NN + s * 64 + lane] / (nrm_i * nrmArr[s * 64 + lane]);

        for (int k = 0; k < TOPK; ++k) {
            double bv = v[0]; int bs = 0;
            #pragma unroll
            for (int s = 1; s < 8; ++s) if (v[s] > bv) { bv = v[s]; bs = s; }
            int bi = bs * 64 + lane;
            #pragma unroll
            for (int off = 32; off > 0; off >>= 1) {
                double ov = __shfl_xor(bv, off);
                int    oi = __shfl_xor(bi, off);
                if (ov > bv || (ov == bv && oi < bi)) { bv = ov; bi = oi; }
            }
            if (lane == 0) topk[i * TOPK + k] = bi;
            if ((bi & 63) == lane) v[bi >> 6] = -1e300;
        }
    }
}

// =============== K3: LDS-staged gather + one-shot softmax + BN atomics =========
__global__ __launch_bounds__(256) void k3_attn(const float* __restrict__ z,
                                               const float* __restrict__ zsrc,
                                               const float* __restrict__ zdst,
                                               const float* __restrict__ es_src,
                                               const float* __restrict__ es_dst,
                                               const int* __restrict__ topk,
                                               const float* __restrict__ emb,
                                               const float* __restrict__ attn_b_p,
                                               float* __restrict__ rst,
                                               double* __restrict__ gstats) {
    __shared__ float  zs[512 * 16];          // 32 KB
    __shared__ double alf_pool[2560];        // 20 KB: alpha[256][20] / BN-reduce alias
    __shared__ unsigned short sIdx[256 * 20];// 10 KB
    float* alf = (float*)alf_pool;
    const float4* alf4 = (const float4*)alf_pool;   // rows are 80 B = 5 float4

    const int b    = blockIdx.x >> 2;
    const int dq   = blockIdx.x & 3;
    const int doff = dq * 16;
    const int t    = threadIdx.x;
    const float attn_b = *attn_b_p;
    const long b512 = (long)b * NN;

    float4* zs4 = (float4*)zs;
    for (int m = t; m < 2048; m += 256) {
        const int n = m >> 2, c4i = m & 3;
        zs4[m] = *(const float4*)(z + (b512 + n) * 64 + doff + c4i * 4);
    }
    __syncthreads();

    const int c4 = t & 3;
    const int rq = t >> 2;
    double s1[4] = {0,0,0,0}, s2[4] = {0,0,0,0};

    for (int chunk = 0; chunk < 2; ++chunk) {
        {
            const int n = chunk * 256 + t;
            const float sd = zdst[b512 + n] + es_dst[n] + attn_b;
            float ev[TOPK];
            float m0 = -1e30f;
            #pragma unroll
            for (int tt = 0; tt < TOPK; ++tt) {
                const int s = topk[n + tt * NN];   // scrambled flat edge list
                sIdx[t * TOPK + tt] = (unsigned short)s;
                float e = zsrc[b512 + s] + es_src[s] + sd;
                e = (e >= 0.f) ? e : 0.2f * e;
                ev[tt] = e;
                m0 = fmaxf(m0, e);
            }
            float dsum = 0.f;
            #pragma unroll
            for (int tt = 0; tt < TOPK; ++tt) { ev[tt] = __expf(ev[tt] - m0); dsum += ev[tt]; }
            const float inv = 1.0f / dsum;
            #pragma unroll
            for (int tt = 0; tt < TOPK; ++tt) alf[t * TOPK + tt] = ev[tt] * inv;
        }
        __syncthreads();

        #pragma unroll
        for (int it = 0; it < 4; ++it) {
            const int nl = it * 64 + rq;
            const int n  = chunk * 256 + nl;
            float4 af[5];
            #pragma unroll
            for (int q = 0; q < 5; ++q) af[q] = alf4[nl * 5 + q];
            const float* av = (const float*)af;
            float4 acc = {0.f, 0.f, 0.f, 0.f};
            #pragma unroll
            for (int tt = 0; tt < TOPK; ++tt) {
                const float a = av[tt];
                const float4 zv = zs4[(int)sIdx[nl * TOPK + tt] * 4 + c4];
                acc.x += a * zv.x; acc.y += a * zv.y; acc.z += a * zv.z; acc.w += a * zv.w;
            }
            const float4 ev = *(const float4*)&emb[n * 64 + doff + c4 * 4];
            float4 r;
            r.x = acc.x * ev.x; r.y = acc.y * ev.y; r.z = acc.z * ev.z; r.w = acc.w * ev.w;
            *(float4*)&rst[(b512 + n) * 64 + doff + c4 * 4] = r;
            s1[0] += (double)r.x; s2[0] += (double)r.x * (double)r.x;
            s1[1] += (double)r.y; s2[1] += (double)r.y * (double)r.y;
            s1[2] += (double)r.z; s2[2] += (double)r.z * (double)r.z;
            s1[3] += (double)r.w; s2[3] += (double)r.w * (double)r.w;
        }
        __syncthreads();
    }

    double* r1 = alf_pool;
    double* r2 = alf_pool + 1024;
    #pragma unroll
    for (int j = 0; j < 4; ++j) {
        r1[(c4 * 4 + j) * 64 + rq] = s1[j];
        r2[(c4 * 4 + j) * 64 + rq] = s2[j];
    }
    __syncthreads();
    if (t < 16) {
        double a = 0.0, bb = 0.0;
        for (int q = 0; q < 64; ++q) { a += r1[t * 64 + q]; bb += r2[t * 64 + q]; }
        atomicAdd(&gstats[doff + t], a);
        atomicAdd(&gstats[64 + doff + t], bb);
    }
}

// =============== K5: BN finalize (per-block) + apply + ReLU + out_w dot ========
__global__ __launch_bounds__(256) void k5_out(const float* __restrict__ rst,
                                              const double* __restrict__ gstats,
                                              const float* __restrict__ gamma,
                                              const float* __restrict__ beta,
                                              const float* __restrict__ out_w,
                                              const float* __restrict__ out_b_p,
                                              float* __restrict__ out) {
    __shared__ float scv[64], biv[64];
    const int t = threadIdx.x;
    if (t < 64) {
        const double M = (double)BB * (double)NN;
        const double s  = gstats[t];
        const double s2 = gstats[64 + t];
        const double mu  = s / M;
        const double var = s2 / M - mu * mu;
        const float scale = (float)((double)gamma[t] / sqrt(var + 1e-5));
        scv[t] = scale;
        biv[t] = beta[t] - (float)mu * scale;
    }
    __syncthreads();

    const int wid = t >> 6, lane = t & 63;
    const float sc = scv[lane], bi = biv[lane], ow = out_w[lane];
    const float ob = *out_b_p;
    const long rowbase = (long)blockIdx.x * 16 + wid * 4;
    float v[4];
    #pragma unroll
    for (int rr = 0; rr < 4; ++rr)
        v[rr] = fmaxf(rst[(rowbase + rr) * 64 + lane] * sc + bi, 0.f) * ow;
    #pragma unroll
    for (int off = 32; off > 0; off >>= 1)
        #pragma unroll
        for (int rr = 0; rr < 4; ++rr) v[rr] += __shfl_down(v[rr], off);
    if (lane == 0)
        #pragma unroll
        for (int rr = 0; rr < 4; ++rr) out[rowbase + rr] = v[rr] + ob;
}

extern "C" void kernel_launch(void* const* d_in, const int* in_sizes, int n_in,
                              void* d_out, int out_size, void* d_ws, size_t ws_size,
                              hipStream_t stream) {
    const float* data   = (const float*)d_in[0];
    const float* emb    = (const float*)d_in[1];
    const float* fc_w   = (const float*)d_in[2];
    const float* fc_b   = (const float*)d_in[3];
    const float* attn_w = (const float*)d_in[4];
    const float* attn_b = (const float*)d_in[5];
    const float* gamma  = (const float*)d_in[6];
    const float* beta   = (const float*)d_in[7];
    const float* out_w  = (const float*)d_in[8];
    const float* out_b  = (const float*)d_in[9];
    float* out = (float*)d_out;

    char* ws = (char*)d_ws;
    float*  z      = (float*) (ws + 0);            // 16 MB
    float*  rst    = (float*) (ws + 16777216);     // 16 MB
    float*  zsrc   = (float*) (ws + 33554432);     // 256 KB
    float*  zdst   = (float*) (ws + 33816576);     // 256 KB
    int*    topk   = (int*)   (ws + 34078720);     // 40 KB
    float*  es_src = (float*) (ws + 34119680);     // 2 KB
    float*  es_dst = (float*) (ws + 34121728);     // 2 KB
    double* gstats = (double*)(ws + 34123776);     // 1 KB
    double* nrm    = (double*)(ws + 34124800);     // 4 KB
    double* cosM   = (double*)(ws + 34131968);     // 2 MB

    kdot_pre<<<260, 256, 0, stream>>>(emb, attn_w, cosM, nrm, es_src, es_dst, gstats);
    kgemm_sel<<<1152, 256, 0, stream>>>(data, fc_w, fc_b, attn_w, cosM, nrm,
                                        z, zsrc, zdst, topk);
    k3_attn<<<BB * 4, 256, 0, stream>>>(z, zsrc, zdst, es_src, es_dst, topk, emb,
                                        attn_b, rst, gstats);
    k5_out<<<4096, 256, 0, stream>>>(rst, gstats, gamma, beta, out_w, out_b, out);
}